// Round 2
// baseline (315.608 us; speedup 1.0000x reference)
//
#include <hip/hip_runtime.h>
#include <hip/hip_bf16.h>

#define B_  1024
#define LA  529   // token positions -> conv channels
#define EE  100   // embedding dim -> conv steps
#define NF  16    // conv filters
#define NT  50    // conv output steps
#define NS  25    // pooled steps
#define NU  100   // LSTM units
#define NJ  400   // 4*NU
#define NBB 2     // batches per block in kernel B

__device__ __forceinline__ float leaky(float v) {
    return v >= 0.f ? v : 0.2f * v;
}

// ---------------- Kernel A: gather + conv + relu + maxpool ----------------
// One WAVE per batch element (4 waves/block). No LDS.
// Lane owns conv step t (0..49): reads emb[tok[c]][2t,2t+1] directly from
// global (L2/L3-resident), weights are wave-uniform -> SGPR via s_load.
__global__ __launch_bounds__(256) void conv_embed_kernel(
    const int*   __restrict__ tokens,
    const float* __restrict__ emb,
    const float* __restrict__ conv_w,   // [2][529][16]
    const float* __restrict__ conv_b,   // [16]
    float*       __restrict__ p_out)    // [B][25][16]
{
    const int lane = threadIdx.x & 63;
    const int wid  = __builtin_amdgcn_readfirstlane(threadIdx.x >> 6);
    const int b    = blockIdx.x * 4 + wid;
    const int t    = lane < NT ? lane : (NT - 1);   // clamp idle lanes to valid row span

    const int* __restrict__ tokb = tokens + (size_t)b * LA;

    float acc[NF];
#pragma unroll
    for (int f = 0; f < NF; ++f) acc[f] = 0.f;

    // software-pipelined over columns, tile = 8
    float2 ebuf[8];
#pragma unroll
    for (int j = 0; j < 8; ++j)
        ebuf[j] = *(const float2*)(emb + (size_t)tokb[j] * EE + 2 * t);

    for (int c0 = 0; c0 < LA - 1; c0 += 8) {   // covers cols 0..527
        float2 enxt[8];
#pragma unroll
        for (int j = 0; j < 8; ++j) {
            const int cn  = c0 + 8 + j;
            const int tok = (cn < LA) ? tokb[cn] : tokb[0];
            enxt[j] = *(const float2*)(emb + (size_t)tok * EE + 2 * t);
        }
#pragma unroll
        for (int j = 0; j < 8; ++j) {
            const float* __restrict__ w0 = conv_w + (size_t)(c0 + j) * NF;
            const float* __restrict__ w1 = conv_w + (size_t)(LA + c0 + j) * NF;
            const float e0 = ebuf[j].x, e1 = ebuf[j].y;
#pragma unroll
            for (int f = 0; f < NF; ++f)
                acc[f] += e0 * w0[f] + e1 * w1[f];
        }
#pragma unroll
        for (int j = 0; j < 8; ++j) ebuf[j] = enxt[j];
    }
    {   // last column (528), prefetched into ebuf[0]
        const float* __restrict__ w0 = conv_w + (size_t)(LA - 1) * NF;
        const float* __restrict__ w1 = conv_w + (size_t)(2 * LA - 1) * NF;
        const float e0 = ebuf[0].x, e1 = ebuf[0].y;
#pragma unroll
        for (int f = 0; f < NF; ++f)
            acc[f] += e0 * w0[f] + e1 * w1[f];
    }

    // bias + relu + maxpool(k=2,s=2) via neighbor-lane shuffle
    float pout[NF];
#pragma unroll
    for (int f = 0; f < NF; ++f) {
        const float v = fmaxf(acc[f] + conv_b[f], 0.f);
        const float o = __shfl_xor(v, 1, 64);
        pout[f] = fmaxf(v, o);
    }
    if (lane < NT && !(lane & 1)) {
        float4* dst = (float4*)(p_out + (size_t)b * (NS * NF) + (size_t)(lane >> 1) * NF);
        dst[0] = ((float4*)pout)[0];
        dst[1] = ((float4*)pout)[1];
        dst[2] = ((float4*)pout)[2];
        dst[3] = ((float4*)pout)[3];
    }
}

// ---------------- Kernel B: LSTM scan + dense head + softmax ----------------
// 512 blocks x 256 threads, NBB=2 batches/block.
// zx = p @ k_lstm + b precomputed into LDS (hoisted out of the 25-step loop).
// z-threads (0..199) own TWO rk columns each (rk[2][100] in registers) ->
// each broadcast h float4 read feeds 8 FMAs.
__global__ __launch_bounds__(256, 2) void lstm_head_kernel(
    const float* __restrict__ p_in,    // [B][25][16]
    const float* __restrict__ k_lstm,  // [16][400]
    const float* __restrict__ rk,      // [100][400]
    const float* __restrict__ b_lstm,  // [400]
    const float* __restrict__ w1,      // [100][64]
    const float* __restrict__ b1,      // [64]
    const float* __restrict__ w2,      // [64][3]
    const float* __restrict__ b2,      // [3]
    float*       __restrict__ out)     // [B][3]
{
    __shared__ __align__(16) float zx_lds[NBB][NS][NJ];   // 80 KB
    __shared__ __align__(16) float p_lds[NBB][NS][NF];
    __shared__ __align__(16) float h_lds[NBB][NU];
    __shared__ float z_lds[NBB][NJ];
    __shared__ float d_lds[NBB * 64];

    const int tid = threadIdx.x;
    const int b0  = blockIdx.x * NBB;

    // stage p (800 floats = 200 float4)
    for (int idx = tid; idx < NBB * NS * NF / 4; idx += 256)
        ((float4*)p_lds)[idx] = ((const float4*)(p_in + (size_t)b0 * (NS * NF)))[idx];
    for (int idx = tid; idx < NBB * NU; idx += 256)
        ((float*)h_lds)[idx] = 0.f;
    __syncthreads();

    // ---- precompute zx[b][t][j] = bias + p[b][t][:] . k_lstm[:, j] ----
    if (tid < 200) {
        float klr[2][NF];
#pragma unroll
        for (int f = 0; f < NF; ++f) {
            klr[0][f] = k_lstm[f * NJ + tid];
            klr[1][f] = k_lstm[f * NJ + 200 + tid];
        }
        const float bl0 = b_lstm[tid], bl1 = b_lstm[200 + tid];
        for (int t = 0; t < NS; ++t) {
            float a00 = bl0, a01 = bl1, a10 = bl0, a11 = bl1;
#pragma unroll
            for (int q = 0; q < 4; ++q) {
                const float4 p0 = ((const float4*)p_lds[0][t])[q];
                const float4 p1 = ((const float4*)p_lds[1][t])[q];
                a00 += p0.x * klr[0][4*q] + p0.y * klr[0][4*q+1] + p0.z * klr[0][4*q+2] + p0.w * klr[0][4*q+3];
                a01 += p0.x * klr[1][4*q] + p0.y * klr[1][4*q+1] + p0.z * klr[1][4*q+2] + p0.w * klr[1][4*q+3];
                a10 += p1.x * klr[0][4*q] + p1.y * klr[0][4*q+1] + p1.z * klr[0][4*q+2] + p1.w * klr[0][4*q+3];
                a11 += p1.x * klr[1][4*q] + p1.y * klr[1][4*q+1] + p1.z * klr[1][4*q+2] + p1.w * klr[1][4*q+3];
            }
            zx_lds[0][t][tid]       = a00;
            zx_lds[0][t][200 + tid] = a01;
            zx_lds[1][t][tid]       = a10;
            zx_lds[1][t][200 + tid] = a11;
        }
    }

    // recurrent weights: 2 columns per z-thread, held in registers
    float rkr[2][NU];
    if (tid < 200) {
#pragma unroll
        for (int k = 0; k < NU; ++k) {
            rkr[0][k] = rk[k * NJ + tid];
            rkr[1][k] = rk[k * NJ + 200 + tid];
        }
    }
    float c_reg = 0.f;
    const int ub = (tid >= NU) ? 1 : 0;     // gate-thread batch (tid < 200)
    const int uu = tid - ub * NU;           // gate-thread unit
    __syncthreads();

#pragma unroll 1
    for (int t = 0; t < NS; ++t) {
        if (tid < 200) {
            float a00 = zx_lds[0][t][tid];
            float a01 = zx_lds[0][t][200 + tid];
            float a10 = zx_lds[1][t][tid];
            float a11 = zx_lds[1][t][200 + tid];
#pragma unroll
            for (int k4 = 0; k4 < NU / 4; ++k4) {
                const float4 h0 = ((const float4*)h_lds[0])[k4];
                const float4 h1 = ((const float4*)h_lds[1])[k4];
                const float r00 = rkr[0][4*k4], r01 = rkr[0][4*k4+1], r02 = rkr[0][4*k4+2], r03 = rkr[0][4*k4+3];
                const float r10 = rkr[1][4*k4], r11 = rkr[1][4*k4+1], r12 = rkr[1][4*k4+2], r13 = rkr[1][4*k4+3];
                a00 += h0.x * r00 + h0.y * r01 + h0.z * r02 + h0.w * r03;
                a01 += h0.x * r10 + h0.y * r11 + h0.z * r12 + h0.w * r13;
                a10 += h1.x * r00 + h1.y * r01 + h1.z * r02 + h1.w * r03;
                a11 += h1.x * r10 + h1.y * r11 + h1.z * r12 + h1.w * r13;
            }
            z_lds[0][tid]       = a00;
            z_lds[0][200 + tid] = a01;
            z_lds[1][tid]       = a10;
            z_lds[1][200 + tid] = a11;
        }
        __syncthreads();
        if (tid < NBB * NU) {
            const float zi = z_lds[ub][uu];
            const float zf = z_lds[ub][NU + uu];
            const float zg = z_lds[ub][2 * NU + uu];
            const float zo = z_lds[ub][3 * NU + uu];
            const float ig  = 1.f / (1.f + __expf(-zi));
            const float fg_ = 1.f / (1.f + __expf(-zf));
            const float og  = 1.f / (1.f + __expf(-zo));
            c_reg = fg_ * c_reg + ig * leaky(zg);
            h_lds[ub][uu] = og * leaky(c_reg);
        }
        __syncthreads();
    }

    // dense head: d = tanh(h @ w1 + b1)
    if (tid < NBB * 64) {
        const int hb = tid >> 6, m = tid & 63;
        float a = b1[m];
#pragma unroll
        for (int u = 0; u < NU; ++u) a += h_lds[hb][u] * w1[u * 64 + m];
        d_lds[tid] = tanhf(a);
    }
    __syncthreads();

    // logits + softmax (3 classes)
    if (tid < NBB) {
        float l0 = b2[0], l1 = b2[1], l2 = b2[2];
        for (int m = 0; m < 64; ++m) {
            const float d = d_lds[tid * 64 + m];
            l0 += d * w2[m * 3 + 0];
            l1 += d * w2[m * 3 + 1];
            l2 += d * w2[m * 3 + 2];
        }
        const float mx = fmaxf(l0, fmaxf(l1, l2));
        const float e0 = __expf(l0 - mx), e1 = __expf(l1 - mx), e2 = __expf(l2 - mx);
        const float inv = 1.f / (e0 + e1 + e2);
        out[(b0 + tid) * 3 + 0] = e0 * inv;
        out[(b0 + tid) * 3 + 1] = e1 * inv;
        out[(b0 + tid) * 3 + 2] = e2 * inv;
    }
}

extern "C" void kernel_launch(void* const* d_in, const int* in_sizes, int n_in,
                              void* d_out, int out_size, void* d_ws, size_t ws_size,
                              hipStream_t stream) {
    const int*   tokens = (const int*)  d_in[0];
    const float* emb    = (const float*)d_in[1];
    const float* conv_w = (const float*)d_in[2];
    const float* conv_b = (const float*)d_in[3];
    const float* k_lstm = (const float*)d_in[4];
    const float* rk     = (const float*)d_in[5];
    const float* b_lstm = (const float*)d_in[6];
    const float* w1     = (const float*)d_in[7];
    const float* b1     = (const float*)d_in[8];
    const float* w2     = (const float*)d_in[9];
    const float* b2     = (const float*)d_in[10];
    float* out  = (float*)d_out;
    float* p_ws = (float*)d_ws;   // [B][25][16] = 1.6 MB

    conv_embed_kernel<<<B_ / 4, 256, 0, stream>>>(tokens, emb, conv_w, conv_b, p_ws);
    lstm_head_kernel<<<B_ / NBB, 256, 0, stream>>>(p_ws, k_lstm, rk, b_lstm,
                                                   w1, b1, w2, b2, out);
}

// Round 3
// 112.003 us; speedup vs baseline: 2.8179x; 2.8179x over previous
//
#include <hip/hip_runtime.h>
#include <hip/hip_bf16.h>

#define B_  1024
#define LA  529   // token positions -> conv channels
#define EE  100   // embedding dim -> conv steps
#define NF  16    // conv filters
#define NT  50    // conv output steps
#define NS  25    // pooled steps
#define NU  100   // LSTM units
#define NJ  400   // 4*NU
#define NBB 2     // batches per block in kernel B
#define PF  8     // e-prefetch depth (columns per wave-group)

__device__ __forceinline__ float leaky(float v) {
    return v >= 0.f ? v : 0.2f * v;
}

// ---------------- Kernel A: gather + conv + relu + maxpool ----------------
// 1024 blocks x 256 threads; block = one batch; wave w handles columns
// c = w + 4*i (strided) -> 16 waves/CU for latency hiding. Weights are
// wave-uniform -> scalar loads; e gathered from global (L3-resident table)
// with an 8-deep software pipeline. Partials reduced via LDS.
__global__ __launch_bounds__(256) void conv_embed_kernel(
    const int*   __restrict__ tokens,
    const float* __restrict__ emb,
    const float* __restrict__ conv_w,   // [2][529][16]
    const float* __restrict__ conv_b,   // [16]
    float*       __restrict__ p_out)    // [B][25][16]
{
    __shared__ int tok_lds[LA];
    __shared__ __align__(16) float part_lds[4][NT][NF];   // 12.8 KB
    __shared__ __align__(16) float y_lds[NT][NF];

    const int tid  = threadIdx.x;
    const int b    = blockIdx.x;
    const int lane = tid & 63;
    const int w    = __builtin_amdgcn_readfirstlane(tid >> 6);
    const int t    = lane < NT ? lane : (NT - 1);

    for (int i = tid; i < LA; i += 256) tok_lds[i] = tokens[(size_t)b * LA + i];
    __syncthreads();

    const int NI = (LA - w + 3) >> 2;   // 133 (w=0) or 132

    float acc[NF];
#pragma unroll
    for (int f = 0; f < NF; ++f) acc[f] = 0.f;

#define LOAD_E(dst, i_) do { \
    const int i2 = (i_); \
    const int ic = (i2 < NI) ? i2 : 0; \
    float2 v = *(const float2*)(emb + (size_t)tok_lds[w + 4 * ic] * EE + 2 * t); \
    if (i2 >= NI) { v.x = 0.f; v.y = 0.f; } \
    (dst) = v; } while (0)

    float2 ebuf[PF];
#pragma unroll
    for (int j = 0; j < PF; ++j) LOAD_E(ebuf[j], j);

    for (int ig = 0; ig < 136; ig += PF) {     // 17 groups covers i=0..135 >= NI
        float2 enxt[PF];
#pragma unroll
        for (int j = 0; j < PF; ++j) LOAD_E(enxt[j], ig + PF + j);
#pragma unroll
        for (int j = 0; j < PF; ++j) {
            const int i  = ig + j;
            const int cc = (i < NI) ? (w + 4 * i) : w;   // uniform; padded cols have e=0
            const float* __restrict__ wp0 = conv_w + (size_t)cc * NF;
            const float* __restrict__ wp1 = conv_w + (size_t)(LA + cc) * NF;
            const float e0 = ebuf[j].x, e1 = ebuf[j].y;
#pragma unroll
            for (int f = 0; f < NF; ++f)
                acc[f] += e0 * wp0[f] + e1 * wp1[f];
        }
#pragma unroll
        for (int j = 0; j < PF; ++j) ebuf[j] = enxt[j];
    }
#undef LOAD_E

    if (lane < NT) {
        float4* dst = (float4*)part_lds[w][lane];
#pragma unroll
        for (int q = 0; q < 4; ++q) dst[q] = ((float4*)acc)[q];
    }
    __syncthreads();

    // reduce 4 wave-partials + bias + relu -> y[50][16]
    if (tid < 200) {
        const int tr = tid >> 2, fq = tid & 3;
        float4 s0 = ((float4*)part_lds[0][tr])[fq];
        float4 s1 = ((float4*)part_lds[1][tr])[fq];
        float4 s2 = ((float4*)part_lds[2][tr])[fq];
        float4 s3 = ((float4*)part_lds[3][tr])[fq];
        float4 cb = ((const float4*)conv_b)[fq];
        float4 y;
        y.x = fmaxf(s0.x + s1.x + s2.x + s3.x + cb.x, 0.f);
        y.y = fmaxf(s0.y + s1.y + s2.y + s3.y + cb.y, 0.f);
        y.z = fmaxf(s0.z + s1.z + s2.z + s3.z + cb.z, 0.f);
        y.w = fmaxf(s0.w + s1.w + s2.w + s3.w + cb.w, 0.f);
        ((float4*)y_lds[tr])[fq] = y;
    }
    __syncthreads();

    // maxpool k=2 s=2 -> p[25][16]
    for (int idx = tid; idx < NS * NF; idx += 256) {
        const int s = idx >> 4, f = idx & 15;
        p_out[(size_t)b * (NS * NF) + idx] = fmaxf(y_lds[2 * s][f], y_lds[2 * s + 1][f]);
    }
}

// ---------------- Kernel B: LSTM scan + dense head + softmax ----------------
// 512 blocks x 256 threads, NBB=2. No zx buffer: input projection folded into
// the step loop (k_lstm staged in LDS). rk columns pinned in VGPRs via asm.
__global__ __launch_bounds__(256, 2) void lstm_head_kernel(
    const float* __restrict__ p_in,    // [B][25][16]
    const float* __restrict__ k_lstm,  // [16][400]
    const float* __restrict__ rk,      // [100][400]
    const float* __restrict__ b_lstm,  // [400]
    const float* __restrict__ w1,      // [100][64]
    const float* __restrict__ b1,      // [64]
    const float* __restrict__ w2,      // [64][3]
    const float* __restrict__ b2,      // [3]
    float*       __restrict__ out)     // [B][3]
{
    __shared__ float kl_lds[NF * NJ];                    // 25.6 KB, [f][j]
    __shared__ __align__(16) float p_lds[NBB][NS][NF];   // 3.2 KB
    __shared__ __align__(16) float h_lds[NBB][NU];
    __shared__ float z_lds[NBB][NJ];
    __shared__ float d_lds[NBB * 64];

    const int tid = threadIdx.x;
    const int b0  = blockIdx.x * NBB;

    for (int idx = tid; idx < NF * NJ; idx += 256) kl_lds[idx] = k_lstm[idx];
    for (int idx = tid; idx < NBB * NS * NF / 4; idx += 256)
        ((float4*)p_lds)[idx] = ((const float4*)(p_in + (size_t)b0 * (NS * NF)))[idx];
    for (int idx = tid; idx < NBB * NU; idx += 256)
        ((float*)h_lds)[idx] = 0.f;

    // recurrent weights: 2 columns per z-thread, register-resident.
    // Unguarded (clamped index) so every lane initializes; asm pin prevents
    // the compiler from rematerializing these as per-step global loads.
    const int j0 = tid < 200 ? tid : 199;
    const int j1 = j0 + 200;
    float rkr0[NU], rkr1[NU];
#pragma unroll
    for (int k = 0; k < NU; ++k) {
        rkr0[k] = rk[k * NJ + j0];
        rkr1[k] = rk[k * NJ + j1];
    }
#pragma unroll
    for (int k = 0; k < NU; ++k)
        asm volatile("" : "+v"(rkr0[k]), "+v"(rkr1[k]));
    const float bl0 = b_lstm[j0], bl1 = b_lstm[j1];

    float c_reg = 0.f;
    const int ub = (tid >= NU) ? 1 : 0;   // gate-thread batch (tid < 200)
    const int uu = tid - ub * NU;
    __syncthreads();

#pragma unroll 1
    for (int t = 0; t < NS; ++t) {
        if (tid < 200) {
            float a00 = bl0, a01 = bl1, a10 = bl0, a11 = bl1;
            // input projection (p broadcast from LDS, k columns conflict-free)
#pragma unroll
            for (int f = 0; f < NF; ++f) {
                const float k0 = kl_lds[f * NJ + j0];
                const float k1 = kl_lds[f * NJ + j1];
                const float p0 = p_lds[0][t][f];
                const float p1 = p_lds[1][t][f];
                a00 += p0 * k0; a01 += p0 * k1;
                a10 += p1 * k0; a11 += p1 * k1;
            }
            // recurrent projection (h broadcast, rk in registers)
#pragma unroll
            for (int k4 = 0; k4 < NU / 4; ++k4) {
                const float4 h0 = ((const float4*)h_lds[0])[k4];
                const float4 h1 = ((const float4*)h_lds[1])[k4];
                a00 += h0.x * rkr0[4*k4] + h0.y * rkr0[4*k4+1] + h0.z * rkr0[4*k4+2] + h0.w * rkr0[4*k4+3];
                a01 += h0.x * rkr1[4*k4] + h0.y * rkr1[4*k4+1] + h0.z * rkr1[4*k4+2] + h0.w * rkr1[4*k4+3];
                a10 += h1.x * rkr0[4*k4] + h1.y * rkr0[4*k4+1] + h1.z * rkr0[4*k4+2] + h1.w * rkr0[4*k4+3];
                a11 += h1.x * rkr1[4*k4] + h1.y * rkr1[4*k4+1] + h1.z * rkr1[4*k4+2] + h1.w * rkr1[4*k4+3];
            }
            z_lds[0][j0] = a00;
            z_lds[0][j1] = a01;
            z_lds[1][j0] = a10;
            z_lds[1][j1] = a11;
        }
        __syncthreads();
        if (tid < NBB * NU) {
            const float zi = z_lds[ub][uu];
            const float zf = z_lds[ub][NU + uu];
            const float zg = z_lds[ub][2 * NU + uu];
            const float zo = z_lds[ub][3 * NU + uu];
            const float ig  = 1.f / (1.f + __expf(-zi));
            const float fg_ = 1.f / (1.f + __expf(-zf));
            const float og  = 1.f / (1.f + __expf(-zo));
            c_reg = fg_ * c_reg + ig * leaky(zg);
            h_lds[ub][uu] = og * leaky(c_reg);
        }
        __syncthreads();
    }

    // dense head: d = tanh(h @ w1 + b1)
    if (tid < NBB * 64) {
        const int hb = tid >> 6, m = tid & 63;
        float a = b1[m];
#pragma unroll
        for (int u = 0; u < NU; ++u) a += h_lds[hb][u] * w1[u * 64 + m];
        d_lds[tid] = tanhf(a);
    }
    __syncthreads();

    // logits + softmax (3 classes)
    if (tid < NBB) {
        float l0 = b2[0], l1 = b2[1], l2 = b2[2];
        for (int m = 0; m < 64; ++m) {
            const float d = d_lds[tid * 64 + m];
            l0 += d * w2[m * 3 + 0];
            l1 += d * w2[m * 3 + 1];
            l2 += d * w2[m * 3 + 2];
        }
        const float mx = fmaxf(l0, fmaxf(l1, l2));
        const float e0 = __expf(l0 - mx), e1 = __expf(l1 - mx), e2 = __expf(l2 - mx);
        const float inv = 1.f / (e0 + e1 + e2);
        out[(b0 + tid) * 3 + 0] = e0 * inv;
        out[(b0 + tid) * 3 + 1] = e1 * inv;
        out[(b0 + tid) * 3 + 2] = e2 * inv;
    }
}

extern "C" void kernel_launch(void* const* d_in, const int* in_sizes, int n_in,
                              void* d_out, int out_size, void* d_ws, size_t ws_size,
                              hipStream_t stream) {
    const int*   tokens = (const int*)  d_in[0];
    const float* emb    = (const float*)d_in[1];
    const float* conv_w = (const float*)d_in[2];
    const float* conv_b = (const float*)d_in[3];
    const float* k_lstm = (const float*)d_in[4];
    const float* rk     = (const float*)d_in[5];
    const float* b_lstm = (const float*)d_in[6];
    const float* w1     = (const float*)d_in[7];
    const float* b1     = (const float*)d_in[8];
    const float* w2     = (const float*)d_in[9];
    const float* b2     = (const float*)d_in[10];
    float* out  = (float*)d_out;
    float* p_ws = (float*)d_ws;   // [B][25][16] = 1.6 MB

    conv_embed_kernel<<<B_, 256, 0, stream>>>(tokens, emb, conv_w, conv_b, p_ws);
    lstm_head_kernel<<<B_ / NBB, 256, 0, stream>>>(p_ws, k_lstm, rk, b_lstm,
                                                   w1, b1, w2, b2, out);
}

// Round 4
// 106.491 us; speedup vs baseline: 2.9637x; 1.0518x over previous
//
#include <hip/hip_runtime.h>
#include <hip/hip_bf16.h>

#define B_  1024
#define LA  529   // token positions -> conv channels
#define EE  100   // embedding dim -> conv steps
#define NF  16    // conv filters
#define NT  50    // conv output steps
#define NS  25    // pooled steps
#define NU  100   // LSTM units
#define NJ  400   // 4*NU
#define PF  8     // e-prefetch depth

typedef float  f32x2  __attribute__((ext_vector_type(2)));
typedef float  f32x4v __attribute__((ext_vector_type(4)));
typedef short  s16x8  __attribute__((ext_vector_type(8)));

__device__ __forceinline__ float leaky(float v) { return v >= 0.f ? v : 0.2f * v; }

union bfu { __hip_bfloat16 b; unsigned short u; };
__device__ __forceinline__ unsigned short f2bf(float x) { bfu t; t.b = __float2bfloat16(x); return t.u; }
__device__ __forceinline__ float bf2f(unsigned short u) { bfu t; t.u = u; return __bfloat162float(t.b); }

// ---------------- Kernel A: gather + conv + relu + maxpool ----------------
// 1024 blocks x 256 threads; block = one batch; wave w owns columns c = w+4i.
// Weights wave-uniform; e gathered from global; inner product via v_pk_fma_f32.
__global__ __launch_bounds__(256) void conv_embed_kernel(
    const int*   __restrict__ tokens,
    const float* __restrict__ emb,
    const float* __restrict__ conv_w,   // [2][529][16]
    const float* __restrict__ conv_b,   // [16]
    float*       __restrict__ p_out)    // [B][25][16]
{
    __shared__ int tok_lds[LA];
    __shared__ __align__(16) float part_lds[4][NT][NF];
    __shared__ __align__(16) float y_lds[NT][NF];

    const int tid  = threadIdx.x;
    const int b    = blockIdx.x;
    const int lane = tid & 63;
    const int w    = __builtin_amdgcn_readfirstlane(tid >> 6);
    const int t    = lane < NT ? lane : (NT - 1);

    for (int i = tid; i < LA; i += 256) tok_lds[i] = tokens[(size_t)b * LA + i];
    __syncthreads();

    const int NI = (LA - w + 3) >> 2;

    f32x2 acc2[8];
#pragma unroll
    for (int p = 0; p < 8; ++p) { acc2[p].x = 0.f; acc2[p].y = 0.f; }

#define LOAD_E(dst, i_) do { \
    const int i2 = (i_); \
    const int ic = (i2 < NI) ? i2 : 0; \
    f32x2 v = *(const f32x2*)(emb + (size_t)tok_lds[w + 4 * ic] * EE + 2 * t); \
    if (i2 >= NI) { v.x = 0.f; v.y = 0.f; } \
    (dst) = v; } while (0)

    f32x2 ebuf[PF];
#pragma unroll
    for (int j = 0; j < PF; ++j) LOAD_E(ebuf[j], j);

    for (int ig = 0; ig < 136; ig += PF) {
        f32x2 enxt[PF];
#pragma unroll
        for (int j = 0; j < PF; ++j) LOAD_E(enxt[j], ig + PF + j);
#pragma unroll
        for (int j = 0; j < PF; ++j) {
            const int i  = ig + j;
            const int cc = (i < NI) ? (w + 4 * i) : w;   // padded cols have e=0
            const f32x2* __restrict__ wp0 = (const f32x2*)(conv_w + (size_t)cc * NF);
            const f32x2* __restrict__ wp1 = (const f32x2*)(conv_w + (size_t)(LA + cc) * NF);
            const f32x2 ev = ebuf[j];
            f32x2 e00; e00.x = ev.x; e00.y = ev.x;
            f32x2 e11; e11.x = ev.y; e11.y = ev.y;
#pragma unroll
            for (int p = 0; p < 8; ++p) {
                f32x2 w0 = wp0[p], w1 = wp1[p];
                asm("v_pk_fma_f32 %0, %1, %2, %0" : "+v"(acc2[p]) : "v"(w0), "v"(e00));
                asm("v_pk_fma_f32 %0, %1, %2, %0" : "+v"(acc2[p]) : "v"(w1), "v"(e11));
            }
        }
#pragma unroll
        for (int j = 0; j < PF; ++j) ebuf[j] = enxt[j];
    }
#undef LOAD_E

    if (lane < NT) {
        float4* dst = (float4*)part_lds[w][lane];
#pragma unroll
        for (int q = 0; q < 4; ++q) dst[q] = ((float4*)acc2)[q];
    }
    __syncthreads();

    if (tid < 200) {
        const int tr = tid >> 2, fq = tid & 3;
        float4 s0 = ((float4*)part_lds[0][tr])[fq];
        float4 s1 = ((float4*)part_lds[1][tr])[fq];
        float4 s2 = ((float4*)part_lds[2][tr])[fq];
        float4 s3 = ((float4*)part_lds[3][tr])[fq];
        float4 cb = ((const float4*)conv_b)[fq];
        float4 y;
        y.x = fmaxf(s0.x + s1.x + s2.x + s3.x + cb.x, 0.f);
        y.y = fmaxf(s0.y + s1.y + s2.y + s3.y + cb.y, 0.f);
        y.z = fmaxf(s0.z + s1.z + s2.z + s3.z + cb.z, 0.f);
        y.w = fmaxf(s0.w + s1.w + s2.w + s3.w + cb.w, 0.f);
        ((float4*)y_lds[tr])[fq] = y;
    }
    __syncthreads();

    for (int idx = tid; idx < NS * NF; idx += 256) {
        const int s = idx >> 4, f = idx & 15;
        p_out[(size_t)b * (NS * NF) + idx] = fmaxf(y_lds[2 * s][f], y_lds[2 * s + 1][f]);
    }
}

// ---------------- Kernel B: MFMA LSTM + dense head + softmax ----------------
// 256 blocks x 512 threads (8 waves), 4 batches/block.
// Z = H_aug @ RK_aug per step via mfma_f32_16x16x32_bf16 with 3-term hi/lo
// split (fp32-accurate). Augmented K = [h(0..99); p_t(100..115); 1(116)].
// RK_aug hi/lo stationary in VGPRs; A (h/p/bias) in lane-linear LDS.
__global__ __launch_bounds__(512, 2) void lstm_mfma_kernel(
    const float* __restrict__ p_in,    // [B][25][16]
    const float* __restrict__ k_lstm,  // [16][400]
    const float* __restrict__ rk,      // [100][400]
    const float* __restrict__ b_lstm,  // [400]
    const float* __restrict__ w1,      // [100][64]
    const float* __restrict__ b1,      // [64]
    const float* __restrict__ w2,      // [64][3]
    const float* __restrict__ b2,      // [3]
    float*       __restrict__ out)     // [B][3]
{
    __shared__ __align__(16) unsigned short a_lds[2][4][64][8]; // [split][chunk][slot][e], 8 KB
    __shared__ __align__(16) float z_lds[NJ][4];                // [j][b], 6.4 KB
    __shared__ float h_f32[4][NU];
    __shared__ float d_lds[4 * 64];

    const int tid  = threadIdx.x;
    const int lane = tid & 63;
    const int wid  = tid >> 6;
    const int b0   = blockIdx.x * 4;

    // zero A-buffer (pad rows b=4..15 and k=117..127 stay 0 forever)
    for (int i = tid; i < 2 * 4 * 64 * 8; i += 512) ((unsigned short*)a_lds)[i] = 0;

    // ---- one-time stationary B-frags: augmented RK, hi/lo split ----
    s16x8 bhi[4][4], blo[4][4];   // [tile][chunk]
#pragma unroll
    for (int i = 0; i < 4; ++i) {
        const int jg = (wid * 4 + i) * 16 + (lane & 15);
#pragma unroll
        for (int c = 0; c < 4; ++c) {
            float v[8];
#pragma unroll
            for (int e = 0; e < 8; ++e) {
                const int k = c * 32 + (lane >> 4) * 8 + e;
                float x = 0.f;
                if (jg < NJ) {
                    if (k < NU)        x = rk[k * NJ + jg];
                    else if (k < 116)  x = k_lstm[(k - NU) * NJ + jg];
                    else if (k == 116) x = b_lstm[jg];
                }
                v[e] = x;
            }
            s16x8 h8, l8;
#pragma unroll
            for (int e = 0; e < 8; ++e) {
                const unsigned short hb = f2bf(v[e]);
                h8[e] = (short)hb;
                l8[e] = (short)f2bf(v[e] - bf2f(hb));
            }
            bhi[i][c] = h8; blo[i][c] = l8;
        }
    }
    __syncthreads();   // a_lds zeroing complete before slot writes

    // initial p (t=0) written by wave 7; bias slot by threads 0..3
    if (tid >= 448) {
        const int idx = tid - 448, pb = idx >> 4, pf = idx & 15;
        const float pv = p_in[(size_t)(b0 + pb) * (NS * NF) + pf];
        const unsigned short ph = f2bf(pv);
        const int k = 100 + pf, c = k >> 5, ls = ((k >> 3) & 3) * 16 + pb, e = k & 7;
        a_lds[0][c][ls][e] = ph;
        a_lds[1][c][ls][e] = f2bf(pv - bf2f(ph));
    }
    if (tid < 4) a_lds[0][3][32 + tid][4] = 0x3F80;   // bias slot k=116: bf16 1.0
    float c_reg = 0.f;
    __syncthreads();

#pragma unroll 1
    for (int t = 0; t < NS; ++t) {
        // wave 7: prefetch p for t+1 (latency hidden under MFMA phase)
        float pv = 0.f;
        if (tid >= 448) {
            const int idx = tid - 448, pb = idx >> 4, pf = idx & 15;
            const int tn = (t + 1 < NS) ? t + 1 : NS - 1;
            pv = p_in[(size_t)(b0 + pb) * (NS * NF) + tn * NF + pf];
        }
        if (wid * 4 < 25) {   // waves 0..6 compute; wave 7 has only pad tiles
            s16x8 ahi[4], alo[4];
#pragma unroll
            for (int c = 0; c < 4; ++c) {
                ahi[c] = ((const s16x8*)a_lds[0][c])[lane];
                alo[c] = ((const s16x8*)a_lds[1][c])[lane];
            }
#pragma unroll
            for (int i = 0; i < 4; ++i) {
                const int ntg = wid * 4 + i;
                if (ntg < 25) {
                    f32x4v acc = {0.f, 0.f, 0.f, 0.f};
#pragma unroll
                    for (int c = 0; c < 4; ++c) {
                        acc = __builtin_amdgcn_mfma_f32_16x16x32_bf16(ahi[c], bhi[i][c], acc, 0, 0, 0);
                        acc = __builtin_amdgcn_mfma_f32_16x16x32_bf16(alo[c], bhi[i][c], acc, 0, 0, 0);
                        acc = __builtin_amdgcn_mfma_f32_16x16x32_bf16(ahi[c], blo[i][c], acc, 0, 0, 0);
                    }
                    if (lane < 16) {   // rows 0..3 = real batches live in lanes 0..15
                        *((f32x4v*)z_lds[ntg * 16 + lane]) = acc;
                    }
                }
            }
        }
        __syncthreads();
        // gates: thread -> (b = tid&3, u = tid>>2); z reads are conflict-free
        if (tid < 4 * NU) {
            const int b = tid & 3, u = tid >> 2;
            const float zi = z_lds[u][b];
            const float zf = z_lds[u + 100][b];
            const float zg = z_lds[u + 200][b];
            const float zo = z_lds[u + 300][b];
            const float ig  = 1.f / (1.f + __expf(-zi));
            const float fg_ = 1.f / (1.f + __expf(-zf));
            const float og  = 1.f / (1.f + __expf(-zo));
            c_reg = fg_ * c_reg + ig * leaky(zg);
            const float h = og * leaky(c_reg);
            h_f32[b][u] = h;
            const unsigned short hh = f2bf(h);
            const unsigned short hl = f2bf(h - bf2f(hh));
            const int c = u >> 5, ls = ((u >> 3) & 3) * 16 + b, e = u & 7;
            a_lds[0][c][ls][e] = hh;
            a_lds[1][c][ls][e] = hl;
        }
        if (tid >= 448) {   // write p slots for t+1
            const int idx = tid - 448, pb = idx >> 4, pf = idx & 15;
            const unsigned short ph = f2bf(pv);
            const int k = 100 + pf, c = k >> 5, ls = ((k >> 3) & 3) * 16 + pb, e = k & 7;
            a_lds[0][c][ls][e] = ph;
            a_lds[1][c][ls][e] = f2bf(pv - bf2f(ph));
        }
        __syncthreads();
    }

    // dense head: d = tanh(h @ w1 + b1)
    if (tid < 256) {
        const int b = tid >> 6, m = tid & 63;
        float a = b1[m];
#pragma unroll 4
        for (int u = 0; u < NU; ++u) a += h_f32[b][u] * w1[u * 64 + m];
        d_lds[b * 64 + m] = tanhf(a);
    }
    __syncthreads();

    // logits + softmax (3 classes)
    if (tid < 4) {
        float l0 = b2[0], l1 = b2[1], l2 = b2[2];
        for (int m = 0; m < 64; ++m) {
            const float d = d_lds[tid * 64 + m];
            l0 += d * w2[m * 3 + 0];
            l1 += d * w2[m * 3 + 1];
            l2 += d * w2[m * 3 + 2];
        }
        const float mx = fmaxf(l0, fmaxf(l1, l2));
        const float e0 = __expf(l0 - mx), e1 = __expf(l1 - mx), e2 = __expf(l2 - mx);
        const float inv = 1.f / (e0 + e1 + e2);
        out[(b0 + tid) * 3 + 0] = e0 * inv;
        out[(b0 + tid) * 3 + 1] = e1 * inv;
        out[(b0 + tid) * 3 + 2] = e2 * inv;
    }
}

extern "C" void kernel_launch(void* const* d_in, const int* in_sizes, int n_in,
                              void* d_out, int out_size, void* d_ws, size_t ws_size,
                              hipStream_t stream) {
    const int*   tokens = (const int*)  d_in[0];
    const float* emb    = (const float*)d_in[1];
    const float* conv_w = (const float*)d_in[2];
    const float* conv_b = (const float*)d_in[3];
    const float* k_lstm = (const float*)d_in[4];
    const float* rk     = (const float*)d_in[5];
    const float* b_lstm = (const float*)d_in[6];
    const float* w1     = (const float*)d_in[7];
    const float* b1     = (const float*)d_in[8];
    const float* w2     = (const float*)d_in[9];
    const float* b2     = (const float*)d_in[10];
    float* out  = (float*)d_out;
    float* p_ws = (float*)d_ws;   // [B][25][16] = 1.6 MB

    conv_embed_kernel<<<B_, 256, 0, stream>>>(tokens, emb, conv_w, conv_b, p_ws);
    lstm_mfma_kernel<<<B_ / 4, 512, 0, stream>>>(p_ws, k_lstm, rk, b_lstm,
                                                 w1, b1, w2, b2, out);
}